// Round 7
// baseline (501.522 us; speedup 1.0000x reference)
//
#include <hip/hip_runtime.h>
#include <hip/hip_bf16.h>

// Sparse conv2d as bf16 implicit GEMM, 256(M) x 224(N) x 64(K).
// A (densified weights) read DIRECT from global (L2-resident) into registers
// (double-buffered, distance-1); B (im2col pixels) staged into a 3-buffer LDS
// rotation at prefetch distance 2 with counted vmcnt (never 0 in the loop).
// x:[32,256,56,56]f32  w_vals:[256,64,3,3]f32  w_idx:[256,64]i32  out:[32,256,56,56]f32
// ws: Wd bf16 [9][256 o][256 c] (1,179,648 B) | Xp bf16 [32][58][58][256] (55,115,776 B)
// Grid 448 tiles of 224 px (3136 = 14*224: tiles never cross b or h-group).

typedef __attribute__((ext_vector_type(8))) short bf16x8;
typedef __attribute__((ext_vector_type(4))) float f32x4;

#define WD_BYTES 1179648
#define XP_BYTES 55115776
#define WS_NEED  (WD_BYTES + XP_BYTES)
#define BUFB     28672            // one B buffer: 224 rows x 128 B
#define LDS_TOT  (3 * BUFB)       // 86016

// ---------------- preprocessing ----------------

// Block o: zero Wd[:, o, :] (only writer of row o), then scatter its 64 taps.
__global__ __launch_bounds__(64) void scatter_w(
    const float* __restrict__ wv, const int* __restrict__ widx,
    __hip_bfloat16* __restrict__ wd)
{
    int o = blockIdx.x, j = threadIdx.x;
#pragma unroll
    for (int k = 0; k < 9; ++k)
        reinterpret_cast<float2*>(wd + (size_t)k * 65536 + o * 256)[j] = float2{0.f, 0.f};
    __syncthreads();
    int cin = widx[o * 64 + j];
    const float* src = wv + (size_t)(o * 64 + j) * 9;
#pragma unroll
    for (int k = 0; k < 9; ++k)
        wd[(size_t)k * 65536 + o * 256 + cin] = __float2bfloat16(src[k]);
}

// Block (b,h): transpose [256 c][56 w] fp32 -> bf16 NHWC padded row h+1,
// plus halo borders (w=0,57 of this row; full rows 0/57 when h==0/55).
__global__ __launch_bounds__(256) void x_to_nhwc(
    const float* __restrict__ x, __hip_bfloat16* __restrict__ xp)
{
    int blk = blockIdx.x;
    int b = blk / 56, h = blk - (blk / 56) * 56;
    __shared__ __hip_bfloat16 tile[56][264];
    int c = threadIdx.x;
    const float* src = x + ((size_t)(b * 256 + c)) * 3136 + h * 56;
    float vals[56];
#pragma unroll
    for (int i = 0; i < 14; ++i) {
        float4 v = *reinterpret_cast<const float4*>(src + i * 4);
        vals[i*4+0] = v.x; vals[i*4+1] = v.y; vals[i*4+2] = v.z; vals[i*4+3] = v.w;
    }
#pragma unroll
    for (int w = 0; w < 56; ++w) tile[w][c] = __float2bfloat16(vals[w]);

    char* rowb = (char*)xp + (((size_t)b * 58 + (h + 1)) * 58) * 512;
    int tid = threadIdx.x;
    if (tid < 64)        reinterpret_cast<double*>(rowb)[tid] = 0.0;
    else if (tid < 128)  *reinterpret_cast<double*>(rowb + 57 * 512 + (tid - 64) * 8) = 0.0;
    if (h == 0) {
        char* r0 = (char*)xp + (((size_t)b * 58 + 0) * 58) * 512;
        for (int i = tid; i < 58 * 64; i += 256) reinterpret_cast<double*>(r0)[i] = 0.0;
    }
    if (h == 55) {
        char* r57 = (char*)xp + (((size_t)b * 58 + 57) * 58) * 512;
        for (int i = tid; i < 58 * 64; i += 256) reinterpret_cast<double*>(r57)[i] = 0.0;
    }

    __syncthreads();
    char* obase = (char*)xp + (((size_t)b * 58 + (h + 1)) * 58) * 512;
#pragma unroll
    for (int k = 0; k < 7; ++k) {
        int i = threadIdx.x + k * 256;
        int w = i >> 5, cc = i & 31;
        bf16x8 v = *reinterpret_cast<const bf16x8*>(&tile[w][cc * 8]);
        *reinterpret_cast<bf16x8*>(obase + (size_t)(w + 1) * 512 + cc * 16) = v;
    }
}

// ---------------- GEMM: A-direct, B via 3-buffer LDS, distance-2 ----------------

__device__ __forceinline__ void gload_lds16(const void* g, void* l) {
    __builtin_amdgcn_global_load_lds(
        (const __attribute__((address_space(1))) void*)g,
        (__attribute__((address_space(3))) void*)l, 16, 0, 0);
}

// B-tile [224 rows][128 B] in buf BB; instr J covers rows J*64 + wid*8 + lane>>3
// (J=3: wid<4 only).
template<int BB, int J>
__device__ __forceinline__ void stage_b(const char* xpB, char* smem, int wid,
                                        int pbJ, int boff) {
    gload_lds16(xpB + pbJ + boff,
                smem + BB * BUFB + (J * 64 + wid * 8) * 128);
}

// B half QN (QN==0: 4 frags, QN==1: 3), rows wc*112 + QN*64 + ni*16.
template<int BB, int QN, int NF>
__device__ __forceinline__ void load_b(const char* smem, int wc, int a_rb,
                                       int xq0, int xq1, bf16x8 (&bfr)[NF][2]) {
#pragma unroll
    for (int ni = 0; ni < (QN ? 3 : 4); ++ni) {
        int base = BB * BUFB + (wc * 112 + QN * 64 + ni * 16) * 128 + a_rb;
        bfr[ni][0] = *(const bf16x8*)(smem + base + xq0);
        bfr[ni][1] = *(const bf16x8*)(smem + base + xq1);
    }
}

__device__ __forceinline__ int pixoff(int p) {   // byte offset of pixel p in Xp
    int b = p / 3136; int r = p - b * 3136;
    int h = r / 56;   int w = r - h * 56;
    return ((b * 58 + h + 1) * 58 + (w + 1)) * 512;
}

__device__ __forceinline__ int aoff_t(int t) {
    return (t >> 2) * 131072 + (t & 3) * 128;
}
__device__ __forceinline__ int boff_t(int t) {   // relative to padded pixoff
    int k9 = t >> 2; int kh = k9 / 3; int kw = k9 - 3 * kh;
    return ((kh - 1) * 58 + (kw - 1)) * 512 + (t & 3) * 128;
}

#define BAR() __builtin_amdgcn_s_barrier()
#define VMCNT22() asm volatile("s_waitcnt vmcnt(22)" ::: "memory")

// Phase for K-tile t (buf U = t%3). Stages B(t+2) into buf W=(t+2)%3, prefetches
// A(t+1) into afn, computes with afc + buf U.
// vmcnt ledger (per wave, wid<4 / wid>=4): ops newer than stage(t).last =
// stage(t+1)[4/3] + A(t)[8] + stage(t+2)[4/3] + A(t+1)[8] = 24/22 -> vmcnt(22)
// guarantees buf U landed (own-wave); the following barrier extends to all waves.
template<int U, int W>
__device__ __forceinline__ void phase(
    const char* xpB, char* smem,
    int wid, int wc, int a_rb, int xq0, int xq1,
    int pb0, int pb1, int pb2, int pb3,
    const char* pAlane, int tStage, int tA,
    bf16x8 (&afc)[4][2], bf16x8 (&afn)[4][2],
    f32x4 (&acc)[4][7])
{
    BAR();      // all waves finished reading buf W (their phase t-1 reads)
    const int bn = boff_t(tStage);
    stage_b<W,0>(xpB, smem, wid, pb0, bn);
    stage_b<W,1>(xpB, smem, wid, pb1, bn);
    stage_b<W,2>(xpB, smem, wid, pb2, bn);
    if (wid < 4) stage_b<W,3>(xpB, smem, wid, pb3, bn);
    const char* pA = pAlane + aoff_t(tA);
#pragma unroll
    for (int mi = 0; mi < 4; ++mi) {
        afn[mi][0] = *(const bf16x8*)(pA + mi * 8192);
        afn[mi][1] = *(const bf16x8*)(pA + mi * 8192 + 64);
    }
    VMCNT22();  // own-wave stage(t) landed (issued 2 phases ago)
    BAR();      // all waves' stage(t) landed -> buf U readable
    bf16x8 b0[4][2], b1[3][2];
    load_b<U,0,4>(smem, wc, a_rb, xq0, xq1, b0);
    load_b<U,1,3>(smem, wc, a_rb, xq0, xq1, b1);
    __builtin_amdgcn_s_setprio(1);
#pragma unroll
    for (int mi = 0; mi < 4; ++mi) {
#pragma unroll
        for (int ni = 0; ni < 4; ++ni)
#pragma unroll
            for (int s = 0; s < 2; ++s)
                acc[mi][ni] = __builtin_amdgcn_mfma_f32_16x16x32_bf16(
                    afc[mi][s], b0[ni][s], acc[mi][ni], 0, 0, 0);
#pragma unroll
        for (int ni = 0; ni < 3; ++ni)
#pragma unroll
            for (int s = 0; s < 2; ++s)
                acc[mi][4+ni] = __builtin_amdgcn_mfma_f32_16x16x32_bf16(
                    afc[mi][s], b1[ni][s], acc[mi][4+ni], 0, 0, 0);
    }
    __builtin_amdgcn_s_setprio(0);
}

__device__ __forceinline__ int wrap36(int t) { return t >= 36 ? t - 36 : t; }

__global__ __launch_bounds__(512, 2) void sparse_conv_mfma224(
    const __hip_bfloat16* __restrict__ wd, const __hip_bfloat16* __restrict__ xp,
    float* __restrict__ out)
{
    extern __shared__ char smem[];
    const char* wdB = (const char*)wd;
    const char* xpB = (const char*)xp;

    const int nt = blockIdx.x;            // 448 N-tiles of 224 px
    const int t = threadIdx.x;
    const int lane = t & 63, wid = t >> 6;
    const int wr = wid >> 1, wc = wid & 1;   // 4M x 2N wave grid

    // B staging constants (pre-swizzled global source, linear LDS dest)
    const int axor = (((lane & 7) ^ (lane >> 3)) * 16);
    const int prow = wid * 8 + (lane >> 3);
    const int pb0 = pixoff(nt * 224 +   0 + prow) + axor;
    const int pb1 = pixoff(nt * 224 +  64 + prow) + axor;
    const int pb2 = pixoff(nt * 224 + 128 + prow) + axor;
    const int pb3 = (wid < 4) ? (pixoff(nt * 224 + 192 + prow) + axor) : 0;

    // B fragment-read constants (XOR matches staging pre-swizzle)
    const int a_rb = (lane & 15) * 128;
    const int xq0 = (((lane >> 4)) ^ (lane & 7)) * 16;
    const int xq1 = ((4 + (lane >> 4)) ^ (lane & 7)) * 16;

    // A direct-load per-lane base: row = wr*64 + (lane&15), k-chunk (lane>>4)*16
    const char* pAlane = wdB + (wr * 64 + (lane & 15)) * 512 + (lane >> 4) * 16;

    f32x4 acc[4][7] = {};
    bf16x8 afA[4][2], afB[4][2];

    // ---- prologue: stage B(0)->buf0, load A(0)->afA, stage B(1)->buf1 ----
    {
        const int b0 = boff_t(0);
        stage_b<0,0>(xpB, smem, wid, pb0, b0);
        stage_b<0,1>(xpB, smem, wid, pb1, b0);
        stage_b<0,2>(xpB, smem, wid, pb2, b0);
        if (wid < 4) stage_b<0,3>(xpB, smem, wid, pb3, b0);
        const char* pA = pAlane + aoff_t(0);
#pragma unroll
        for (int mi = 0; mi < 4; ++mi) {
            afA[mi][0] = *(const bf16x8*)(pA + mi * 8192);
            afA[mi][1] = *(const bf16x8*)(pA + mi * 8192 + 64);
        }
        const int b1 = boff_t(1);
        stage_b<1,0>(xpB, smem, wid, pb0, b1);
        stage_b<1,1>(xpB, smem, wid, pb1, b1);
        stage_b<1,2>(xpB, smem, wid, pb2, b1);
        if (wid < 4) stage_b<1,3>(xpB, smem, wid, pb3, b1);
    }

    // ---- main loop: 36 phases, 6 per iteration (buffer pattern period 6) ----
    for (int it = 0; it < 6; ++it) {
        const int t0 = 6 * it;
        phase<0,2>(xpB, smem, wid, wc, a_rb, xq0, xq1, pb0, pb1, pb2, pb3,
                   pAlane, wrap36(t0 + 2), wrap36(t0 + 1), afA, afB, acc);
        phase<1,0>(xpB, smem, wid, wc, a_rb, xq0, xq1, pb0, pb1, pb2, pb3,
                   pAlane, wrap36(t0 + 3), wrap36(t0 + 2), afB, afA, acc);
        phase<2,1>(xpB, smem, wid, wc, a_rb, xq0, xq1, pb0, pb1, pb2, pb3,
                   pAlane, wrap36(t0 + 4), wrap36(t0 + 3), afA, afB, acc);
        phase<0,2>(xpB, smem, wid, wc, a_rb, xq0, xq1, pb0, pb1, pb2, pb3,
                   pAlane, wrap36(t0 + 5), wrap36(t0 + 4), afB, afA, acc);
        phase<1,0>(xpB, smem, wid, wc, a_rb, xq0, xq1, pb0, pb1, pb2, pb3,
                   pAlane, wrap36(t0 + 6), wrap36(t0 + 5), afA, afB, acc);
        phase<2,1>(xpB, smem, wid, wc, a_rb, xq0, xq1, pb0, pb1, pb2, pb3,
                   pAlane, wrap36(t0 + 7), wrap36(t0 + 6), afB, afA, acc);
    }

    // ---- epilogue: out[b][o][px] ----
#pragma unroll
    for (int n = 0; n < 7; ++n) {
        int p0 = nt * 224 + wc * 112 + n * 16;   // wave-uniform; 16 | 3136
        int pb = p0 / 3136;
        int rem0 = p0 - pb * 3136;
#pragma unroll
        for (int m = 0; m < 4; ++m) {
            int o = wr * 64 + m * 16 + (lane >> 4) * 4;
            float* dst = out + ((size_t)(pb * 256 + o)) * 3136 + rem0 + (lane & 15);
#pragma unroll
            for (int r = 0; r < 4; ++r) dst[(size_t)r * 3136] = acc[m][n][r];
        }
    }
}

// ---------------- fallback (ws too small) ----------------

__global__ __launch_bounds__(256) void sparse_conv_direct(
    const float* __restrict__ x, const float* __restrict__ wv,
    const int* __restrict__ widx, float* __restrict__ out)
{
    const int bid = blockIdx.x;
    const int b = bid >> 8, o = bid & 255;
    const int tid = threadIdx.x;
    __shared__ float plane[58 * 60];
    const int rt = tid >> 3, ct = tid & 7;
    const int r0 = rt * 2, c0 = ct * 7;
    const bool active = (rt < 28);
    float acc[2][7];
#pragma unroll
    for (int i = 0; i < 2; ++i)
#pragma unroll
        for (int c = 0; c < 7; ++c) acc[i][c] = 0.f;
    const float* xb = x + (size_t)b * 256 * 3136;
    const int* idxp = widx + o * 64;
    const float* wp0 = wv + (size_t)o * 64 * 9;
    for (int j = 0; j < 64; ++j) {
        const int cin = idxp[j];
        const float* src = xb + cin * 3136;
        __syncthreads();
        for (int i = tid; i < 58 * 58; i += 256) {
            const int r = i / 58, c = i - r * 58;
            const int h = r - 1, w = c - 1;
            float v = 0.f;
            if ((unsigned)h < 56u && (unsigned)w < 56u) v = src[h * 56 + w];
            plane[r * 60 + c] = v;
        }
        float wreg[9];
#pragma unroll
        for (int k = 0; k < 9; ++k) wreg[k] = wp0[j * 9 + k];
        __syncthreads();
        if (active) {
            float rows[4][9];
#pragma unroll
            for (int dr = 0; dr < 4; ++dr)
#pragma unroll
                for (int cc = 0; cc < 9; ++cc)
                    rows[dr][cc] = plane[(r0 + dr) * 60 + (c0 + cc)];
#pragma unroll
            for (int i = 0; i < 2; ++i)
#pragma unroll
                for (int cc = 0; cc < 7; ++cc) {
                    float s = acc[i][cc];
#pragma unroll
                    for (int kh = 0; kh < 3; ++kh)
#pragma unroll
                        for (int kw = 0; kw < 3; ++kw)
                            s += rows[i + kh][cc + kw] * wreg[kh * 3 + kw];
                    acc[i][cc] = s;
                }
        }
    }
    if (active) {
        float* op = out + (size_t)bid * 3136;
#pragma unroll
        for (int i = 0; i < 2; ++i)
#pragma unroll
            for (int cc = 0; cc < 7; ++cc)
                op[(r0 + i) * 56 + (c0 + cc)] = acc[i][cc];
    }
}

extern "C" void kernel_launch(void* const* d_in, const int* in_sizes, int n_in,
                              void* d_out, int out_size, void* d_ws, size_t ws_size,
                              hipStream_t stream) {
    const float* x    = (const float*)d_in[0];
    const float* wv   = (const float*)d_in[1];
    const int*   widx = (const int*)d_in[2];
    float* out = (float*)d_out;
    (void)in_sizes; (void)n_in; (void)out_size;

    if (ws_size < (size_t)WS_NEED) {
        sparse_conv_direct<<<dim3(32 * 256), dim3(256), 0, stream>>>(x, wv, widx, out);
        return;
    }

    __hip_bfloat16* wd = (__hip_bfloat16*)d_ws;
    __hip_bfloat16* xp = (__hip_bfloat16*)((char*)d_ws + WD_BYTES);

    scatter_w<<<dim3(256), dim3(64), 0, stream>>>(wv, widx, wd);
    x_to_nhwc<<<dim3(32 * 56), dim3(256), 0, stream>>>(x, xp);

    (void)hipFuncSetAttribute((const void*)sparse_conv_mfma224,
                              hipFuncAttributeMaxDynamicSharedMemorySize, LDS_TOT);
    sparse_conv_mfma224<<<dim3(448), dim3(512), LDS_TOT, stream>>>(wd, xp, out);
}

// Round 8
// 268.530 us; speedup vs baseline: 1.8677x; 1.8677x over previous
//
#include <hip/hip_runtime.h>
#include <hip/hip_bf16.h>

// Sparse conv2d as bf16 implicit GEMM, 256(M) x 224(N) x 64(K).
// A (densified weights) read DIRECT from global (L2-resident, 1.15 MB) into
// registers at phase start; B (im2col pixels) double-buffered in LDS with the
// round-5 proven 2-buffer / 4-barrier-per-K-tile schedule.
// x:[32,256,56,56]f32  w_vals:[256,64,3,3]f32  w_idx:[256,64]i32  out:[32,256,56,56]f32
// ws: Wd bf16 [9][256 o][256 c] (1,179,648 B) | Xp bf16 [32][58][58][256] (55,115,776 B)
// Grid 448 tiles of 224 px (3136 = 14*224: tiles never cross b or h-group).

typedef __attribute__((ext_vector_type(8))) short bf16x8;
typedef __attribute__((ext_vector_type(4))) float f32x4;

#define WD_BYTES 1179648
#define XP_BYTES 55115776
#define WS_NEED  (WD_BYTES + XP_BYTES)
#define BUFB     28672            // one B buffer: 224 rows x 128 B
#define LDS_TOT  (2 * BUFB)       // 57344

// ---------------- preprocessing ----------------

// Block o: zero Wd[:, o, :] (only writer of row o), then scatter its 64 taps.
__global__ __launch_bounds__(64) void scatter_w(
    const float* __restrict__ wv, const int* __restrict__ widx,
    __hip_bfloat16* __restrict__ wd)
{
    int o = blockIdx.x, j = threadIdx.x;
#pragma unroll
    for (int k = 0; k < 9; ++k)
        reinterpret_cast<float2*>(wd + (size_t)k * 65536 + o * 256)[j] = float2{0.f, 0.f};
    __syncthreads();
    int cin = widx[o * 64 + j];
    const float* src = wv + (size_t)(o * 64 + j) * 9;
#pragma unroll
    for (int k = 0; k < 9; ++k)
        wd[(size_t)k * 65536 + o * 256 + cin] = __float2bfloat16(src[k]);
}

// Block (b,h): transpose [256 c][56 w] fp32 -> bf16 NHWC padded row h+1,
// plus halo borders (w=0,57 of this row; full rows 0/57 when h==0/55).
__global__ __launch_bounds__(256) void x_to_nhwc(
    const float* __restrict__ x, __hip_bfloat16* __restrict__ xp)
{
    int blk = blockIdx.x;
    int b = blk / 56, h = blk - (blk / 56) * 56;
    __shared__ __hip_bfloat16 tile[56][264];
    int c = threadIdx.x;
    const float* src = x + ((size_t)(b * 256 + c)) * 3136 + h * 56;
    float vals[56];
#pragma unroll
    for (int i = 0; i < 14; ++i) {
        float4 v = *reinterpret_cast<const float4*>(src + i * 4);
        vals[i*4+0] = v.x; vals[i*4+1] = v.y; vals[i*4+2] = v.z; vals[i*4+3] = v.w;
    }
#pragma unroll
    for (int w = 0; w < 56; ++w) tile[w][c] = __float2bfloat16(vals[w]);

    char* rowb = (char*)xp + (((size_t)b * 58 + (h + 1)) * 58) * 512;
    int tid = threadIdx.x;
    if (tid < 64)        reinterpret_cast<double*>(rowb)[tid] = 0.0;
    else if (tid < 128)  *reinterpret_cast<double*>(rowb + 57 * 512 + (tid - 64) * 8) = 0.0;
    if (h == 0) {
        char* r0 = (char*)xp + (((size_t)b * 58 + 0) * 58) * 512;
        for (int i = tid; i < 58 * 64; i += 256) reinterpret_cast<double*>(r0)[i] = 0.0;
    }
    if (h == 55) {
        char* r57 = (char*)xp + (((size_t)b * 58 + 57) * 58) * 512;
        for (int i = tid; i < 58 * 64; i += 256) reinterpret_cast<double*>(r57)[i] = 0.0;
    }

    __syncthreads();
    char* obase = (char*)xp + (((size_t)b * 58 + (h + 1)) * 58) * 512;
#pragma unroll
    for (int k = 0; k < 7; ++k) {
        int i = threadIdx.x + k * 256;
        int w = i >> 5, cc = i & 31;
        bf16x8 v = *reinterpret_cast<const bf16x8*>(&tile[w][cc * 8]);
        *reinterpret_cast<bf16x8*>(obase + (size_t)(w + 1) * 512 + cc * 16) = v;
    }
}

// ---------------- GEMM: A-direct, B via 2-buffer LDS (R5 schedule) ----------------

__device__ __forceinline__ void gload_lds16(const void* g, void* l) {
    __builtin_amdgcn_global_load_lds(
        (const __attribute__((address_space(1))) void*)g,
        (__attribute__((address_space(3))) void*)l, 16, 0, 0);
}

// B-tile [224 rows][128 B] in buf BB; instr J covers rows J*64 + wid*8 + lane>>3
// (J=3: wid<4 only).
template<int BB, int J>
__device__ __forceinline__ void stage_b(const char* xpB, char* smem, int wid,
                                        int pbJ, int boff) {
    gload_lds16(xpB + pbJ + boff,
                smem + BB * BUFB + (J * 64 + wid * 8) * 128);
}

// B half QN (QN==0: 4 frags, QN==1: 3), rows wc*112 + QN*64 + ni*16.
template<int BB, int QN, int NF>
__device__ __forceinline__ void load_b(const char* smem, int wc, int a_rb,
                                       int xq0, int xq1, bf16x8 (&bfr)[NF][2]) {
#pragma unroll
    for (int ni = 0; ni < (QN ? 3 : 4); ++ni) {
        int base = BB * BUFB + (wc * 112 + QN * 64 + ni * 16) * 128 + a_rb;
        bfr[ni][0] = *(const bf16x8*)(smem + base + xq0);
        bfr[ni][1] = *(const bf16x8*)(smem + base + xq1);
    }
}

template<int QN, int NF>
__device__ __forceinline__ void mfma_half(bf16x8 (&af)[4][2], bf16x8 (&bfr)[NF][2],
                                          f32x4 (&acc)[4][7]) {
    __builtin_amdgcn_s_setprio(1);
#pragma unroll
    for (int mi = 0; mi < 4; ++mi)
#pragma unroll
        for (int ni = 0; ni < (QN ? 3 : 4); ++ni)
#pragma unroll
            for (int s = 0; s < 2; ++s)
                acc[mi][QN*4+ni] = __builtin_amdgcn_mfma_f32_16x16x32_bf16(
                    af[mi][s], bfr[ni][s], acc[mi][QN*4+ni], 0, 0, 0);
    __builtin_amdgcn_s_setprio(0);
}

__device__ __forceinline__ int pixoff(int p) {   // byte offset of pixel p in Xp
    int b = p / 3136; int r = p - b * 3136;
    int h = r / 56;   int w = r - h * 56;
    return ((b * 58 + h + 1) * 58 + (w + 1)) * 512;
}

__device__ __forceinline__ int aoff_t(int t) {
    return (t >> 2) * 131072 + (t & 3) * 128;
}
__device__ __forceinline__ int boff_t(int t) {   // relative to padded pixoff
    int k9 = t >> 2; int kh = k9 / 3; int kw = k9 - 3 * kh;
    return ((kh - 1) * 58 + (kw - 1)) * 512 + (t & 3) * 128;
}

#define BAR() __builtin_amdgcn_s_barrier()
#define VMCNT0() asm volatile("s_waitcnt vmcnt(0)" ::: "memory")

// One K-tile pair-phase on buf U. A(t) loaded direct from global FIRST (so the
// compiler's wait before MFMA leaves the newer B-stages in flight); B(tn)
// staged into buf 1-U; end-of-pair drain covers a full pair (~2k cyc).
template<int U>
__device__ __forceinline__ void phasepair(
    const char* xpB, char* smem, int wid, int wc, int a_rb, int xq0, int xq1,
    int pb0, int pb1, int pb2, int pb3,
    const char* pAlane, int t, int tn,
    f32x4 (&acc)[4][7])
{
    // P1: A(t) direct (8 gl) -> stage B(tn)->buf 1-U -> 8 ds_read B-h0(buf U)
    bf16x8 af[4][2];
    const char* pA = pAlane + aoff_t(t);
#pragma unroll
    for (int mi = 0; mi < 4; ++mi) {
        af[mi][0] = *(const bf16x8*)(pA + mi * 8192);
        af[mi][1] = *(const bf16x8*)(pA + mi * 8192 + 64);
    }
    const int bn = boff_t(tn);
    stage_b<1-U,0>(xpB, smem, wid, pb0, bn);
    stage_b<1-U,1>(xpB, smem, wid, pb1, bn);
    stage_b<1-U,2>(xpB, smem, wid, pb2, bn);
    if (wid < 4) stage_b<1-U,3>(xpB, smem, wid, pb3, bn);
    bf16x8 b0[4][2];
    load_b<U,0,4>(smem, wc, a_rb, xq0, xq1, b0);
    BAR();
    mfma_half<0>(af, b0, acc);
    BAR();
    // P2: 6 ds_read B-h1(buf U); drain stages at end (cover = full pair)
    bf16x8 b1[3][2];
    load_b<U,1,3>(smem, wc, a_rb, xq0, xq1, b1);
    BAR();
    mfma_half<1>(af, b1, acc);
    VMCNT0();
    BAR();
}

__global__ __launch_bounds__(512, 2) void sparse_conv_mfma224(
    const __hip_bfloat16* __restrict__ wd, const __hip_bfloat16* __restrict__ xp,
    float* __restrict__ out)
{
    extern __shared__ char smem[];
    const char* wdB = (const char*)wd;
    const char* xpB = (const char*)xp;

    const int nt = blockIdx.x;            // 448 N-tiles of 224 px
    const int t = threadIdx.x;
    const int lane = t & 63, wid = t >> 6;
    const int wr = wid >> 1, wc = wid & 1;   // 4M x 2N wave grid

    // B staging constants (pre-swizzled global source, linear LDS dest)
    const int axor = (((lane & 7) ^ (lane >> 3)) * 16);
    const int prow = wid * 8 + (lane >> 3);
    const int pb0 = pixoff(nt * 224 +   0 + prow) + axor;
    const int pb1 = pixoff(nt * 224 +  64 + prow) + axor;
    const int pb2 = pixoff(nt * 224 + 128 + prow) + axor;
    const int pb3 = (wid < 4) ? (pixoff(nt * 224 + 192 + prow) + axor) : 0;

    // B fragment-read constants (XOR matches staging pre-swizzle)
    const int a_rb = (lane & 15) * 128;
    const int xq0 = (((lane >> 4)) ^ (lane & 7)) * 16;
    const int xq1 = ((4 + (lane >> 4)) ^ (lane & 7)) * 16;

    // A direct-load per-lane base: row = wr*64 + (lane&15), k-chunk (lane>>4)*16
    const char* pAlane = wdB + (wr * 64 + (lane & 15)) * 512 + (lane >> 4) * 16;

    f32x4 acc[4][7] = {};

    // ---- prologue: stage B(0)->buf0, drain, barrier ----
    {
        const int b0 = boff_t(0);
        stage_b<0,0>(xpB, smem, wid, pb0, b0);
        stage_b<0,1>(xpB, smem, wid, pb1, b0);
        stage_b<0,2>(xpB, smem, wid, pb2, b0);
        if (wid < 4) stage_b<0,3>(xpB, smem, wid, pb3, b0);
        VMCNT0();
        BAR();
    }

    // ---- main loop: 18 iterations x 2 K-tiles (36 total) ----
    for (int it = 0; it < 18; ++it) {
        const int t0 = 2 * it, t1 = 2 * it + 1;
        int t2 = t1 + 1; if (t2 == 36) t2 = 0;    // wrapped dead staging
        phasepair<0>(xpB, smem, wid, wc, a_rb, xq0, xq1, pb0, pb1, pb2, pb3,
                     pAlane, t0, t1, acc);        // reads buf0, stages B(t1)->buf1
        phasepair<1>(xpB, smem, wid, wc, a_rb, xq0, xq1, pb0, pb1, pb2, pb3,
                     pAlane, t1, t2, acc);        // reads buf1, stages B(t2)->buf0
    }

    // ---- epilogue: out[b][o][px] ----
#pragma unroll
    for (int n = 0; n < 7; ++n) {
        int p0 = nt * 224 + wc * 112 + n * 16;   // wave-uniform; 16 | 3136
        int pb = p0 / 3136;
        int rem0 = p0 - pb * 3136;
#pragma unroll
        for (int m = 0; m < 4; ++m) {
            int o = wr * 64 + m * 16 + (lane >> 4) * 4;
            float* dst = out + ((size_t)(pb * 256 + o)) * 3136 + rem0 + (lane & 15);
#pragma unroll
            for (int r = 0; r < 4; ++r) dst[(size_t)r * 3136] = acc[m][n][r];
        }
    }
}

// ---------------- fallback (ws too small) ----------------

__global__ __launch_bounds__(256) void sparse_conv_direct(
    const float* __restrict__ x, const float* __restrict__ wv,
    const int* __restrict__ widx, float* __restrict__ out)
{
    const int bid = blockIdx.x;
    const int b = bid >> 8, o = bid & 255;
    const int tid = threadIdx.x;
    __shared__ float plane[58 * 60];
    const int rt = tid >> 3, ct = tid & 7;
    const int r0 = rt * 2, c0 = ct * 7;
    const bool active = (rt < 28);
    float acc[2][7];
#pragma unroll
    for (int i = 0; i < 2; ++i)
#pragma unroll
        for (int c = 0; c < 7; ++c) acc[i][c] = 0.f;
    const float* xb = x + (size_t)b * 256 * 3136;
    const int* idxp = widx + o * 64;
    const float* wp0 = wv + (size_t)o * 64 * 9;
    for (int j = 0; j < 64; ++j) {
        const int cin = idxp[j];
        const float* src = xb + cin * 3136;
        __syncthreads();
        for (int i = tid; i < 58 * 58; i += 256) {
            const int r = i / 58, c = i - r * 58;
            const int h = r - 1, w = c - 1;
            float v = 0.f;
            if ((unsigned)h < 56u && (unsigned)w < 56u) v = src[h * 56 + w];
            plane[r * 60 + c] = v;
        }
        float wreg[9];
#pragma unroll
        for (int k = 0; k < 9; ++k) wreg[k] = wp0[j * 9 + k];
        __syncthreads();
        if (active) {
            float rows[4][9];
#pragma unroll
            for (int dr = 0; dr < 4; ++dr)
#pragma unroll
                for (int cc = 0; cc < 9; ++cc)
                    rows[dr][cc] = plane[(r0 + dr) * 60 + (c0 + cc)];
#pragma unroll
            for (int i = 0; i < 2; ++i)
#pragma unroll
                for (int cc = 0; cc < 7; ++cc) {
                    float s = acc[i][cc];
#pragma unroll
                    for (int kh = 0; kh < 3; ++kh)
#pragma unroll
                        for (int kw = 0; kw < 3; ++kw)
                            s += rows[i + kh][cc + kw] * wreg[kh * 3 + kw];
                    acc[i][cc] = s;
                }
        }
    }
    if (active) {
        float* op = out + (size_t)bid * 3136;
#pragma unroll
        for (int i = 0; i < 2; ++i)
#pragma unroll
            for (int cc = 0; cc < 7; ++cc)
                op[(r0 + i) * 56 + (c0 + cc)] = acc[i][cc];
    }
}

extern "C" void kernel_launch(void* const* d_in, const int* in_sizes, int n_in,
                              void* d_out, int out_size, void* d_ws, size_t ws_size,
                              hipStream_t stream) {
    const float* x    = (const float*)d_in[0];
    const float* wv   = (const float*)d_in[1];
    const int*   widx = (const int*)d_in[2];
    float* out = (float*)d_out;
    (void)in_sizes; (void)n_in; (void)out_size;

    if (ws_size < (size_t)WS_NEED) {
        sparse_conv_direct<<<dim3(32 * 256), dim3(256), 0, stream>>>(x, wv, widx, out);
        return;
    }

    __hip_bfloat16* wd = (__hip_bfloat16*)d_ws;
    __hip_bfloat16* xp = (__hip_bfloat16*)((char*)d_ws + WD_BYTES);

    scatter_w<<<dim3(256), dim3(64), 0, stream>>>(wv, widx, wd);
    x_to_nhwc<<<dim3(32 * 56), dim3(256), 0, stream>>>(x, xp);

    (void)hipFuncSetAttribute((const void*)sparse_conv_mfma224,
                              hipFuncAttributeMaxDynamicSharedMemorySize, LDS_TOT);
    sparse_conv_mfma224<<<dim3(448), dim3(512), LDS_TOT, stream>>>(wd, xp, out);
}

// Round 9
// 166.038 us; speedup vs baseline: 3.0205x; 1.6173x over previous
//
#include <hip/hip_runtime.h>
#include <hip/hip_bf16.h>

// Sparse conv2d as bf16 implicit GEMM, 256(M) x 224(N) x 64(K).
// 4 waves, wave tile 128x112 (acc[8][7]) -> LDS reads/FLOP cut 32% vs 64x112;
// A+B double-buffered in LDS; 1 barrier + 1 covered vmcnt(0) per K-tile.
// x:[32,256,56,56]f32  w_vals:[256,64,3,3]f32  w_idx:[256,64]i32  out:[32,256,56,56]f32
// ws: Wd bf16 [9][256 o][256 c] (1,179,648 B) | Xp bf16 [32][58][58][256] (55,115,776 B)
// Grid 448 tiles of 224 px (3136 = 14*224: tiles never cross b or h-group).

typedef __attribute__((ext_vector_type(8))) short bf16x8;
typedef __attribute__((ext_vector_type(4))) float f32x4;

#define WD_BYTES 1179648
#define XP_BYTES 55115776
#define WS_NEED  (WD_BYTES + XP_BYTES)
// LDS: A0 [0,32K) A1 [32K,64K) B0 [64K,92K) B1 [92K,120K)
#define ABUF 32768
#define BBUF 28672
#define BOFF 65536
#define LDS_TOT 122880

// ---------------- fused preprocessing ----------------
// Blocks [0,1792): transpose x (b,h) -> Xp NHWC bf16 + halo zeros.
// Blocks [1792,2048): zero+scatter Wd row o = bid-1792.
__global__ __launch_bounds__(256) void preproc(
    const float* __restrict__ x, const float* __restrict__ wv,
    const int* __restrict__ widx, __hip_bfloat16* __restrict__ wd,
    __hip_bfloat16* __restrict__ xp)
{
    int bid = blockIdx.x;
    int tid = threadIdx.x;
    if (bid >= 1792) {              // ---- scatter_w ----
        int o = bid - 1792;
        int j = tid & 63;
        if (tid < 64) {
#pragma unroll
            for (int k = 0; k < 9; ++k)
                reinterpret_cast<float2*>(wd + (size_t)k * 65536 + o * 256)[j] =
                    float2{0.f, 0.f};
        }
        __syncthreads();
        if (tid < 64) {
            int cin = widx[o * 64 + j];
            const float* src = wv + (size_t)(o * 64 + j) * 9;
#pragma unroll
            for (int k = 0; k < 9; ++k)
                wd[(size_t)k * 65536 + o * 256 + cin] = __float2bfloat16(src[k]);
        }
        return;
    }
    // ---- x_to_nhwc ----
    int b = bid / 56, h = bid - (bid / 56) * 56;
    __shared__ __hip_bfloat16 tile[56][264];
    int c = tid;
    const float* src = x + ((size_t)(b * 256 + c)) * 3136 + h * 56;
    float vals[56];
#pragma unroll
    for (int i = 0; i < 14; ++i) {
        float4 v = *reinterpret_cast<const float4*>(src + i * 4);
        vals[i*4+0] = v.x; vals[i*4+1] = v.y; vals[i*4+2] = v.z; vals[i*4+3] = v.w;
    }
#pragma unroll
    for (int w = 0; w < 56; ++w) tile[w][c] = __float2bfloat16(vals[w]);

    char* rowb = (char*)xp + (((size_t)b * 58 + (h + 1)) * 58) * 512;
    if (tid < 64)        reinterpret_cast<double*>(rowb)[tid] = 0.0;
    else if (tid < 128)  *reinterpret_cast<double*>(rowb + 57 * 512 + (tid - 64) * 8) = 0.0;
    if (h == 0) {
        char* r0 = (char*)xp + (((size_t)b * 58 + 0) * 58) * 512;
        for (int i = tid; i < 58 * 64; i += 256) reinterpret_cast<double*>(r0)[i] = 0.0;
    }
    if (h == 55) {
        char* r57 = (char*)xp + (((size_t)b * 58 + 57) * 58) * 512;
        for (int i = tid; i < 58 * 64; i += 256) reinterpret_cast<double*>(r57)[i] = 0.0;
    }

    __syncthreads();
    char* obase = (char*)xp + (((size_t)b * 58 + (h + 1)) * 58) * 512;
#pragma unroll
    for (int k = 0; k < 7; ++k) {
        int i = tid + k * 256;
        int w = i >> 5, cc = i & 31;
        bf16x8 v = *reinterpret_cast<const bf16x8*>(&tile[w][cc * 8]);
        *reinterpret_cast<bf16x8*>(obase + (size_t)(w + 1) * 512 + cc * 16) = v;
    }
}

// ---------------- GEMM ----------------

__device__ __forceinline__ void gload_lds16(const void* g, void* l) {
    __builtin_amdgcn_global_load_lds(
        (const __attribute__((address_space(1))) void*)g,
        (__attribute__((address_space(3))) void*)l, 16, 0, 0);
}

// A-tile [256 rows][128 B]; instr J (0..7) covers rows J*32 + wid*8 + lane>>3.
template<int BB, int J>
__device__ __forceinline__ void stage_a(const char* wdB, char* smem, int wid,
                                        int sa_off, int aoff) {
    gload_lds16(wdB + aoff + J * 32 * 512 + sa_off,
                smem + BB * ABUF + (J * 32 + wid * 8) * 128);
}

// B-tile [224 rows][128 B]; instr J (0..6) covers rows J*32 + wid*8 + lane>>3.
template<int BB, int J>
__device__ __forceinline__ void stage_b(const char* xpB, char* smem, int wid,
                                        int pbJ, int boff) {
    gload_lds16(xpB + pbJ + boff,
                smem + BOFF + BB * BBUF + (J * 32 + wid * 8) * 128);
}

__device__ __forceinline__ int pixoff(int p) {   // byte offset of pixel p in Xp
    int b = p / 3136; int r = p - b * 3136;
    int h = r / 56;   int w = r - h * 56;
    return ((b * 58 + h + 1) * 58 + (w + 1)) * 512;
}

__device__ __forceinline__ int aoff_t(int t) {
    return (t >> 2) * 131072 + (t & 3) * 128;
}
__device__ __forceinline__ int boff_t(int t) {   // relative to padded pixoff
    int k9 = t >> 2; int kh = k9 / 3; int kw = k9 - 3 * kh;
    return ((kh - 1) * 58 + (kw - 1)) * 512 + (t & 3) * 128;
}

#define BAR() __builtin_amdgcn_s_barrier()
#define VMCNT0() asm volatile("s_waitcnt vmcnt(0)" ::: "memory")

// One K-tile on buf U; stages tile tn into buf 1-U (drain covered by ~2200 cyc
// of MFMA). 15 gload_lds + 30 ds_read_b128 + 112 MFMA per wave.
template<int U>
__device__ __forceinline__ void ktile(
    const char* wdB, const char* xpB, char* smem,
    int wid, int wr, int wc, int a_rb, int xq0, int xq1, int sa_off,
    int pb0, int pb1, int pb2, int pb3, int pb4, int pb5, int pb6,
    int tn, f32x4 (&acc)[8][7])
{
    // stage tile tn -> buf 1-U
    const int an = aoff_t(tn), bn = boff_t(tn);
    stage_a<1-U,0>(wdB, smem, wid, sa_off, an);
    stage_a<1-U,1>(wdB, smem, wid, sa_off, an);
    stage_a<1-U,2>(wdB, smem, wid, sa_off, an);
    stage_a<1-U,3>(wdB, smem, wid, sa_off, an);
    stage_a<1-U,4>(wdB, smem, wid, sa_off, an);
    stage_a<1-U,5>(wdB, smem, wid, sa_off, an);
    stage_a<1-U,6>(wdB, smem, wid, sa_off, an);
    stage_a<1-U,7>(wdB, smem, wid, sa_off, an);
    stage_b<1-U,0>(xpB, smem, wid, pb0, bn);
    stage_b<1-U,1>(xpB, smem, wid, pb1, bn);
    stage_b<1-U,2>(xpB, smem, wid, pb2, bn);
    stage_b<1-U,3>(xpB, smem, wid, pb3, bn);
    stage_b<1-U,4>(xpB, smem, wid, pb4, bn);
    stage_b<1-U,5>(xpB, smem, wid, pb5, bn);
    stage_b<1-U,6>(xpB, smem, wid, pb6, bn);

    const int aBase = U * ABUF + wr * 128 * 128 + a_rb;
    const int bBase = BOFF + U * BBUF + wc * 112 * 128 + a_rb;

#pragma unroll
    for (int ks = 0; ks < 2; ++ks) {
        const int xq = ks ? xq1 : xq0;
        bf16x8 af[8], bf[7];
#pragma unroll
        for (int mi = 0; mi < 8; ++mi)
            af[mi] = *(const bf16x8*)(smem + aBase + mi * 16 * 128 + xq);
#pragma unroll
        for (int ni = 0; ni < 7; ++ni)
            bf[ni] = *(const bf16x8*)(smem + bBase + ni * 16 * 128 + xq);
        __builtin_amdgcn_s_setprio(1);
#pragma unroll
        for (int mi = 0; mi < 8; ++mi)
#pragma unroll
            for (int ni = 0; ni < 7; ++ni)
                acc[mi][ni] = __builtin_amdgcn_mfma_f32_16x16x32_bf16(
                    af[mi], bf[ni], acc[mi][ni], 0, 0, 0);
        __builtin_amdgcn_s_setprio(0);
    }
    VMCNT0();   // stage(tn) drained; issued ~2200 cyc ago
    BAR();      // buf 1-U ready for next iter; all waves done reading buf U
}

__global__ __launch_bounds__(256, 1) void sparse_conv_mfma224(
    const __hip_bfloat16* __restrict__ wd, const __hip_bfloat16* __restrict__ xp,
    float* __restrict__ out)
{
    extern __shared__ char smem[];
    const char* wdB = (const char*)wd;
    const char* xpB = (const char*)xp;

    const int nt = blockIdx.x;            // 448 N-tiles of 224 px
    const int t = threadIdx.x;
    const int lane = t & 63, wid = t >> 6;   // 4 waves
    const int wr = wid >> 1, wc = wid & 1;   // 2M x 2N wave grid

    // staging constants (pre-swizzled global source, linear LDS dest)
    const int axor = (((lane & 7) ^ (lane >> 3)) * 16);
    const int sa_off = (wid * 8 + (lane >> 3)) * 512 + axor;
    const int prow = wid * 8 + (lane >> 3);
    const int pb0 = pixoff(nt * 224 +   0 + prow) + axor;
    const int pb1 = pixoff(nt * 224 +  32 + prow) + axor;
    const int pb2 = pixoff(nt * 224 +  64 + prow) + axor;
    const int pb3 = pixoff(nt * 224 +  96 + prow) + axor;
    const int pb4 = pixoff(nt * 224 + 128 + prow) + axor;
    const int pb5 = pixoff(nt * 224 + 160 + prow) + axor;
    const int pb6 = pixoff(nt * 224 + 192 + prow) + axor;

    // fragment-read constants (XOR matches staging pre-swizzle)
    const int a_rb = (lane & 15) * 128;
    const int xq0 = (((lane >> 4)) ^ (lane & 7)) * 16;
    const int xq1 = ((4 + (lane >> 4)) ^ (lane & 7)) * 16;

    f32x4 acc[8][7] = {};

    // ---- prologue: stage tile 0 -> buf0 ----
    {
        const int a0 = aoff_t(0), b0 = boff_t(0);
        stage_a<0,0>(wdB, smem, wid, sa_off, a0);
        stage_a<0,1>(wdB, smem, wid, sa_off, a0);
        stage_a<0,2>(wdB, smem, wid, sa_off, a0);
        stage_a<0,3>(wdB, smem, wid, sa_off, a0);
        stage_a<0,4>(wdB, smem, wid, sa_off, a0);
        stage_a<0,5>(wdB, smem, wid, sa_off, a0);
        stage_a<0,6>(wdB, smem, wid, sa_off, a0);
        stage_a<0,7>(wdB, smem, wid, sa_off, a0);
        stage_b<0,0>(xpB, smem, wid, pb0, b0);
        stage_b<0,1>(xpB, smem, wid, pb1, b0);
        stage_b<0,2>(xpB, smem, wid, pb2, b0);
        stage_b<0,3>(xpB, smem, wid, pb3, b0);
        stage_b<0,4>(xpB, smem, wid, pb4, b0);
        stage_b<0,5>(xpB, smem, wid, pb5, b0);
        stage_b<0,6>(xpB, smem, wid, pb6, b0);
        VMCNT0();
        BAR();
    }

    // ---- main loop: 18 iterations x 2 K-tiles (36 total) ----
    for (int it = 0; it < 18; ++it) {
        const int t1 = 2 * it + 1;
        int t2 = t1 + 1; if (t2 == 36) t2 = 0;   // wrapped dead staging
        ktile<0>(wdB, xpB, smem, wid, wr, wc, a_rb, xq0, xq1, sa_off,
                 pb0, pb1, pb2, pb3, pb4, pb5, pb6, t1, acc);
        ktile<1>(wdB, xpB, smem, wid, wr, wc, a_rb, xq0, xq1, sa_off,
                 pb0, pb1, pb2, pb3, pb4, pb5, pb6, t2, acc);
    }

    // ---- epilogue: out[b][o][px] ----
#pragma unroll
    for (int n = 0; n < 7; ++n) {
        int p0 = nt * 224 + wc * 112 + n * 16;   // wave-uniform; 16 | 3136
        int pb = p0 / 3136;
        int rem0 = p0 - pb * 3136;
#pragma unroll
        for (int m = 0; m < 8; ++m) {
            int o = wr * 128 + m * 16 + (lane >> 4) * 4;
            float* dst = out + ((size_t)(pb * 256 + o)) * 3136 + rem0 + (lane & 15);
#pragma unroll
            for (int r = 0; r < 4; ++r) dst[(size_t)r * 3136] = acc[m][n][r];
        }
    }
}

// ---------------- fallback (ws too small) ----------------

__global__ __launch_bounds__(256) void sparse_conv_direct(
    const float* __restrict__ x, const float* __restrict__ wv,
    const int* __restrict__ widx, float* __restrict__ out)
{
    const int bid = blockIdx.x;
    const int b = bid >> 8, o = bid & 255;
    const int tid = threadIdx.x;
    __shared__ float plane[58 * 60];
    const int rt = tid >> 3, ct = tid & 7;
    const int r0 = rt * 2, c0 = ct * 7;
    const bool active = (rt < 28);
    float acc[2][7];
#pragma unroll
    for (int i = 0; i < 2; ++i)
#pragma unroll
        for (int c = 0; c < 7; ++c) acc[i][c] = 0.f;
    const float* xb = x + (size_t)b * 256 * 3136;
    const int* idxp = widx + o * 64;
    const float* wp0 = wv + (size_t)o * 64 * 9;
    for (int j = 0; j < 64; ++j) {
        const int cin = idxp[j];
        const float* src = xb + cin * 3136;
        __syncthreads();
        for (int i = tid; i < 58 * 58; i += 256) {
            const int r = i / 58, c = i - r * 58;
            const int h = r - 1, w = c - 1;
            float v = 0.f;
            if ((unsigned)h < 56u && (unsigned)w < 56u) v = src[h * 56 + w];
            plane[r * 60 + c] = v;
        }
        float wreg[9];
#pragma unroll
        for (int k = 0; k < 9; ++k) wreg[k] = wp0[j * 9 + k];
        __syncthreads();
        if (active) {
            float rows[4][9];
#pragma unroll
            for (int dr = 0; dr < 4; ++dr)
#pragma unroll
                for (int cc = 0; cc < 9; ++cc)
                    rows[dr][cc] = plane[(r0 + dr) * 60 + (c0 + cc)];
#pragma unroll
            for (int i = 0; i < 2; ++i)
#pragma unroll
                for (int cc = 0; cc < 7; ++cc) {
                    float s = acc[i][cc];
#pragma unroll
                    for (int kh = 0; kh < 3; ++kh)
#pragma unroll
                        for (int kw = 0; kw < 3; ++kw)
                            s += rows[i + kh][cc + kw] * wreg[kh * 3 + kw];
                    acc[i][cc] = s;
                }
        }
    }
    if (active) {
        float* op = out + (size_t)bid * 3136;
#pragma unroll
        for (int i = 0; i < 2; ++i)
#pragma unroll
            for (int cc = 0; cc < 7; ++cc)
                op[(r0 + i) * 56 + (c0 + cc)] = acc[i][cc];
    }
}

extern "C" void kernel_launch(void* const* d_in, const int* in_sizes, int n_in,
                              void* d_out, int out_size, void* d_ws, size_t ws_size,
                              hipStream_t stream) {
    const float* x    = (const float*)d_in[0];
    const float* wv   = (const float*)d_in[1];
    const int*   widx = (const int*)d_in[2];
    float* out = (float*)d_out;
    (void)in_sizes; (void)n_in; (void)out_size;

    if (ws_size < (size_t)WS_NEED) {
        sparse_conv_direct<<<dim3(32 * 256), dim3(256), 0, stream>>>(x, wv, widx, out);
        return;
    }

    __hip_bfloat16* wd = (__hip_bfloat16*)d_ws;
    __hip_bfloat16* xp = (__hip_bfloat16*)((char*)d_ws + WD_BYTES);

    preproc<<<dim3(32 * 56 + 256), dim3(256), 0, stream>>>(x, wv, widx, wd, xp);

    (void)hipFuncSetAttribute((const void*)sparse_conv_mfma224,
                              hipFuncAttributeMaxDynamicSharedMemorySize, LDS_TOT);
    sparse_conv_mfma224<<<dim3(448), dim3(256), LDS_TOT, stream>>>(wd, xp, out);
}

// Round 10
// 151.548 us; speedup vs baseline: 3.3093x; 1.0956x over previous
//
#include <hip/hip_runtime.h>
#include <hip/hip_bf16.h>

// Sparse conv2d as bf16 implicit GEMM, 256(M) x 224(N) x 64(K).
// 8 waves (4M x 2N, wave tile 64x112, acc[4][7] -> 2 waves/SIMD), A+B
// double-buffered in LDS, ONE barrier + one covered vmcnt(0) per K-tile.
// x:[32,256,56,56]f32  w_vals:[256,64,3,3]f32  w_idx:[256,64]i32  out:[32,256,56,56]f32
// ws: Wd bf16 [9][256 o][256 c] (1,179,648 B) | Xp bf16 [32][58][58][256] (55,115,776 B)
// Grid 448 tiles of 224 px (3136 = 14*224: tiles never cross b or h-group).

typedef __attribute__((ext_vector_type(8))) short bf16x8;
typedef __attribute__((ext_vector_type(4))) float f32x4;

#define WD_BYTES 1179648
#define XP_BYTES 55115776
#define WS_NEED  (WD_BYTES + XP_BYTES)
// LDS: A0 [0,32K) A1 [32K,64K) B0 [64K,92K) B1 [92K,120K)
#define ABUF 32768
#define BBUF 28672
#define BOFF 65536
#define LDS_TOT 122880

// ---------------- fused preprocessing ----------------
// Blocks [0,1792): transpose x (b,h) -> Xp NHWC bf16 + halo zeros.
// Blocks [1792,2048): zero+scatter Wd row o = bid-1792.
__global__ __launch_bounds__(256) void preproc(
    const float* __restrict__ x, const float* __restrict__ wv,
    const int* __restrict__ widx, __hip_bfloat16* __restrict__ wd,
    __hip_bfloat16* __restrict__ xp)
{
    int bid = blockIdx.x;
    int tid = threadIdx.x;
    if (bid >= 1792) {              // ---- scatter_w ----
        int o = bid - 1792;
        int j = tid & 63;
        if (tid < 64) {
#pragma unroll
            for (int k = 0; k < 9; ++k)
                reinterpret_cast<float2*>(wd + (size_t)k * 65536 + o * 256)[j] =
                    float2{0.f, 0.f};
        }
        __syncthreads();
        if (tid < 64) {
            int cin = widx[o * 64 + j];
            const float* src = wv + (size_t)(o * 64 + j) * 9;
#pragma unroll
            for (int k = 0; k < 9; ++k)
                wd[(size_t)k * 65536 + o * 256 + cin] = __float2bfloat16(src[k]);
        }
        return;
    }
    // ---- x_to_nhwc ----
    int b = bid / 56, h = bid - (bid / 56) * 56;
    __shared__ __hip_bfloat16 tile[56][264];
    int c = tid;
    const float* src = x + ((size_t)(b * 256 + c)) * 3136 + h * 56;
    float vals[56];
#pragma unroll
    for (int i = 0; i < 14; ++i) {
        float4 v = *reinterpret_cast<const float4*>(src + i * 4);
        vals[i*4+0] = v.x; vals[i*4+1] = v.y; vals[i*4+2] = v.z; vals[i*4+3] = v.w;
    }
#pragma unroll
    for (int w = 0; w < 56; ++w) tile[w][c] = __float2bfloat16(vals[w]);

    char* rowb = (char*)xp + (((size_t)b * 58 + (h + 1)) * 58) * 512;
    if (tid < 64)        reinterpret_cast<double*>(rowb)[tid] = 0.0;
    else if (tid < 128)  *reinterpret_cast<double*>(rowb + 57 * 512 + (tid - 64) * 8) = 0.0;
    if (h == 0) {
        char* r0 = (char*)xp + (((size_t)b * 58 + 0) * 58) * 512;
        for (int i = tid; i < 58 * 64; i += 256) reinterpret_cast<double*>(r0)[i] = 0.0;
    }
    if (h == 55) {
        char* r57 = (char*)xp + (((size_t)b * 58 + 57) * 58) * 512;
        for (int i = tid; i < 58 * 64; i += 256) reinterpret_cast<double*>(r57)[i] = 0.0;
    }

    __syncthreads();
    char* obase = (char*)xp + (((size_t)b * 58 + (h + 1)) * 58) * 512;
#pragma unroll
    for (int k = 0; k < 7; ++k) {
        int i = tid + k * 256;
        int w = i >> 5, cc = i & 31;
        bf16x8 v = *reinterpret_cast<const bf16x8*>(&tile[w][cc * 8]);
        *reinterpret_cast<bf16x8*>(obase + (size_t)(w + 1) * 512 + cc * 16) = v;
    }
}

// ---------------- GEMM ----------------

__device__ __forceinline__ void gload_lds16(const void* g, void* l) {
    __builtin_amdgcn_global_load_lds(
        (const __attribute__((address_space(1))) void*)g,
        (__attribute__((address_space(3))) void*)l, 16, 0, 0);
}

// A-tile [256 rows][128 B]; instr J (0..3) covers rows J*64 + wid*8 + lane>>3
// (512 threads: one instr stages 8 KB = 64 rows).
template<int BB, int J>
__device__ __forceinline__ void stage_a(const char* wdB, char* smem, int wid,
                                        int sa_off, int aoff) {
    gload_lds16(wdB + aoff + J * 64 * 512 + sa_off,
                smem + BB * ABUF + (J * 64 + wid * 8) * 128);
}

// B-tile [224 rows][128 B]; instr J (0..3) covers rows J*64 + wid*8 + lane>>3
// (J=3: only 32 rows -> wid<4).
template<int BB, int J>
__device__ __forceinline__ void stage_b(const char* xpB, char* smem, int wid,
                                        int pbJ, int boff) {
    gload_lds16(xpB + pbJ + boff,
                smem + BOFF + BB * BBUF + (J * 64 + wid * 8) * 128);
}

__device__ __forceinline__ int pixoff(int p) {   // byte offset of pixel p in Xp
    int b = p / 3136; int r = p - b * 3136;
    int h = r / 56;   int w = r - h * 56;
    return ((b * 58 + h + 1) * 58 + (w + 1)) * 512;
}

__device__ __forceinline__ int aoff_t(int t) {
    return (t >> 2) * 131072 + (t & 3) * 128;
}
__device__ __forceinline__ int boff_t(int t) {   // relative to padded pixoff
    int k9 = t >> 2; int kh = k9 / 3; int kw = k9 - 3 * kh;
    return ((kh - 1) * 58 + (kw - 1)) * 512 + (t & 3) * 128;
}

#define BAR() __builtin_amdgcn_s_barrier()
#define VMCNT0() asm volatile("s_waitcnt vmcnt(0)" ::: "memory")

// One K-tile on buf U; stages tile tn into buf 1-U. Per wave: 7.5 gload_lds +
// 22 ds_read_b128 + one 56-MFMA cluster; vmcnt(0) covered by the cluster;
// single barrier per K-tile. WAR safe: all buf-U reads complete before the
// cluster's last MFMA, which precedes the barrier.
template<int U>
__device__ __forceinline__ void ktile(
    const char* wdB, const char* xpB, char* smem,
    int wid, int wr, int wc, int a_rb, int xq0, int xq1, int sa_off,
    int pb0, int pb1, int pb2, int pb3,
    int tn, f32x4 (&acc)[4][7])
{
    // stage tile tn -> buf 1-U
    const int an = aoff_t(tn), bn = boff_t(tn);
    stage_a<1-U,0>(wdB, smem, wid, sa_off, an);
    stage_a<1-U,1>(wdB, smem, wid, sa_off, an);
    stage_a<1-U,2>(wdB, smem, wid, sa_off, an);
    stage_a<1-U,3>(wdB, smem, wid, sa_off, an);
    stage_b<1-U,0>(xpB, smem, wid, pb0, bn);
    stage_b<1-U,1>(xpB, smem, wid, pb1, bn);
    stage_b<1-U,2>(xpB, smem, wid, pb2, bn);
    if (wid < 4) stage_b<1-U,3>(xpB, smem, wid, pb3, bn);

    const int aBase = U * ABUF + wr * 64 * 128 + a_rb;
    const int bBase = BOFF + U * BBUF + wc * 112 * 128 + a_rb;

    bf16x8 af[4][2], bf[7][2];
#pragma unroll
    for (int mi = 0; mi < 4; ++mi) {
        af[mi][0] = *(const bf16x8*)(smem + aBase + mi * 16 * 128 + xq0);
        af[mi][1] = *(const bf16x8*)(smem + aBase + mi * 16 * 128 + xq1);
    }
#pragma unroll
    for (int ni = 0; ni < 7; ++ni) {
        bf[ni][0] = *(const bf16x8*)(smem + bBase + ni * 16 * 128 + xq0);
        bf[ni][1] = *(const bf16x8*)(smem + bBase + ni * 16 * 128 + xq1);
    }
    __builtin_amdgcn_s_setprio(1);
#pragma unroll
    for (int mi = 0; mi < 4; ++mi)
#pragma unroll
        for (int ni = 0; ni < 7; ++ni)
#pragma unroll
            for (int s = 0; s < 2; ++s)
                acc[mi][ni] = __builtin_amdgcn_mfma_f32_16x16x32_bf16(
                    af[mi][s], bf[ni][s], acc[mi][ni], 0, 0, 0);
    __builtin_amdgcn_s_setprio(0);

    VMCNT0();   // own stage(tn) drained; issued ~1500+ cyc ago, TLP covers
    BAR();      // buf 1-U ready; all waves done reading buf U
}

__global__ __launch_bounds__(512, 2) void sparse_conv_mfma224(
    const __hip_bfloat16* __restrict__ wd, const __hip_bfloat16* __restrict__ xp,
    float* __restrict__ out)
{
    extern __shared__ char smem[];
    const char* wdB = (const char*)wd;
    const char* xpB = (const char*)xp;

    const int nt = blockIdx.x;            // 448 N-tiles of 224 px
    const int t = threadIdx.x;
    const int lane = t & 63, wid = t >> 6;   // 8 waves
    const int wr = wid >> 1, wc = wid & 1;   // 4M x 2N wave grid

    // staging constants (pre-swizzled global source, linear LDS dest)
    const int axor = (((lane & 7) ^ (lane >> 3)) * 16);
    const int sa_off = (wid * 8 + (lane >> 3)) * 512 + axor;
    const int prow = wid * 8 + (lane >> 3);
    const int pb0 = pixoff(nt * 224 +   0 + prow) + axor;
    const int pb1 = pixoff(nt * 224 +  64 + prow) + axor;
    const int pb2 = pixoff(nt * 224 + 128 + prow) + axor;
    const int pb3 = (wid < 4) ? (pixoff(nt * 224 + 192 + prow) + axor) : 0;

    // fragment-read constants (XOR matches staging pre-swizzle)
    const int a_rb = (lane & 15) * 128;
    const int xq0 = (((lane >> 4)) ^ (lane & 7)) * 16;
    const int xq1 = ((4 + (lane >> 4)) ^ (lane & 7)) * 16;

    f32x4 acc[4][7] = {};

    // ---- prologue: stage tile 0 -> buf0 ----
    {
        const int a0 = aoff_t(0), b0 = boff_t(0);
        stage_a<0,0>(wdB, smem, wid, sa_off, a0);
        stage_a<0,1>(wdB, smem, wid, sa_off, a0);
        stage_a<0,2>(wdB, smem, wid, sa_off, a0);
        stage_a<0,3>(wdB, smem, wid, sa_off, a0);
        stage_b<0,0>(xpB, smem, wid, pb0, b0);
        stage_b<0,1>(xpB, smem, wid, pb1, b0);
        stage_b<0,2>(xpB, smem, wid, pb2, b0);
        if (wid < 4) stage_b<0,3>(xpB, smem, wid, pb3, b0);
        VMCNT0();
        BAR();
    }

    // ---- main loop: 18 iterations x 2 K-tiles (36 total) ----
    for (int it = 0; it < 18; ++it) {
        const int t1 = 2 * it + 1;
        int t2 = t1 + 1; if (t2 == 36) t2 = 0;   // wrapped dead staging
        ktile<0>(wdB, xpB, smem, wid, wr, wc, a_rb, xq0, xq1, sa_off,
                 pb0, pb1, pb2, pb3, t1, acc);
        ktile<1>(wdB, xpB, smem, wid, wr, wc, a_rb, xq0, xq1, sa_off,
                 pb0, pb1, pb2, pb3, t2, acc);
    }

    // ---- epilogue: out[b][o][px] ----
#pragma unroll
    for (int n = 0; n < 7; ++n) {
        int p0 = nt * 224 + wc * 112 + n * 16;   // wave-uniform; 16 | 3136
        int pb = p0 / 3136;
        int rem0 = p0 - pb * 3136;
#pragma unroll
        for (int m = 0; m < 4; ++m) {
            int o = wr * 64 + m * 16 + (lane >> 4) * 4;
            float* dst = out + ((size_t)(pb * 256 + o)) * 3136 + rem0 + (lane & 15);
#pragma unroll
            for (int r = 0; r < 4; ++r) dst[(size_t)r * 3136] = acc[m][n][r];
        }
    }
}

// ---------------- fallback (ws too small) ----------------

__global__ __launch_bounds__(256) void sparse_conv_direct(
    const float* __restrict__ x, const float* __restrict__ wv,
    const int* __restrict__ widx, float* __restrict__ out)
{
    const int bid = blockIdx.x;
    const int b = bid >> 8, o = bid & 255;
    const int tid = threadIdx.x;
    __shared__ float plane[58 * 60];
    const int rt = tid >> 3, ct = tid & 7;
    const int r0 = rt * 2, c0 = ct * 7;
    const bool active = (rt < 28);
    float acc[2][7];
#pragma unroll
    for (int i = 0; i < 2; ++i)
#pragma unroll
        for (int c = 0; c < 7; ++c) acc[i][c] = 0.f;
    const float* xb = x + (size_t)b * 256 * 3136;
    const int* idxp = widx + o * 64;
    const float* wp0 = wv + (size_t)o * 64 * 9;
    for (int j = 0; j < 64; ++j) {
        const int cin = idxp[j];
        const float* src = xb + cin * 3136;
        __syncthreads();
        for (int i = tid; i < 58 * 58; i += 256) {
            const int r = i / 58, c = i - r * 58;
            const int h = r - 1, w = c - 1;
            float v = 0.f;
            if ((unsigned)h < 56u && (unsigned)w < 56u) v = src[h * 56 + w];
            plane[r * 60 + c] = v;
        }
        float wreg[9];
#pragma unroll
        for (int k = 0; k < 9; ++k) wreg[k] = wp0[j * 9 + k];
        __syncthreads();
        if (active) {
            float rows[4][9];
#pragma unroll
            for (int dr = 0; dr < 4; ++dr)
#pragma unroll
                for (int cc = 0; cc < 9; ++cc)
                    rows[dr][cc] = plane[(r0 + dr) * 60 + (c0 + cc)];
#pragma unroll
            for (int i = 0; i < 2; ++i)
#pragma unroll
                for (int cc = 0; cc < 7; ++cc) {
                    float s = acc[i][cc];
#pragma unroll
                    for (int kh = 0; kh < 3; ++kh)
#pragma unroll
                        for (int kw = 0; kw < 3; ++kw)
                            s += rows[i + kh][cc + kw] * wreg[kh * 3 + kw];
                    acc[i][cc] = s;
                }
        }
    }
    if (active) {
        float* op = out + (size_t)bid * 3136;
#pragma unroll
        for (int i = 0; i < 2; ++i)
#pragma unroll
            for (int cc = 0; cc < 7; ++cc)
                op[(r0 + i) * 56 + (c0 + cc)] = acc[i][cc];
    }
}

extern "C" void kernel_launch(void* const* d_in, const int* in_sizes, int n_in,
                              void* d_out, int out_size, void* d_ws, size_t ws_size,
                              hipStream_t stream) {
    const float* x    = (const float*)d_in[0];
    const float* wv   = (const float*)d_in[1];
    const int*   widx = (const int*)d_in[2];
    float* out = (float*)d_out;
    (void)in_sizes; (void)n_in; (void)out_size;

    if (ws_size < (size_t)WS_NEED) {
        sparse_conv_direct<<<dim3(32 * 256), dim3(256), 0, stream>>>(x, wv, widx, out);
        return;
    }

    __hip_bfloat16* wd = (__hip_bfloat16*)d_ws;
    __hip_bfloat16* xp = (__hip_bfloat16*)((char*)d_ws + WD_BYTES);

    preproc<<<dim3(32 * 56 + 256), dim3(256), 0, stream>>>(x, wv, widx, wd, xp);

    (void)hipFuncSetAttribute((const void*)sparse_conv_mfma224,
                              hipFuncAttributeMaxDynamicSharedMemorySize, LDS_TOT);
    sparse_conv_mfma224<<<dim3(448), dim3(512), LDS_TOT, stream>>>(wd, xp, out);
}

// Round 11
// 148.398 us; speedup vs baseline: 3.3796x; 1.0212x over previous
//
#include <hip/hip_runtime.h>
#include <hip/hip_bf16.h>

// Sparse conv2d as bf16 implicit GEMM, 256(M) x 224(N) x 64(K).
// 8 waves (4M x 2N, wave tile 64x112), A+B double-buffered in LDS, ONE
// barrier + one covered vmcnt(0) per K-tile. Reads are CONSUMPTION-ORDERED
// (af0,bf0 first) so the first MFMA unlocks after 2 reads, overlapping the
// LDS-read ramp with the MFMA cluster instead of alternating pipe bursts.
// x:[32,256,56,56]f32  w_vals:[256,64,3,3]f32  w_idx:[256,64]i32  out:[32,256,56,56]f32
// ws: Wd bf16 [9][256 o][256 c] | Xp bf16 [32][58][58][256]
// Grid 448 tiles of 224 px (3136 = 14*224), bijective XCD swizzle (448=8*56).

typedef __attribute__((ext_vector_type(8))) short bf16x8;
typedef __attribute__((ext_vector_type(4))) float f32x4;

#define WD_BYTES 1179648
#define XP_BYTES 55115776
#define WS_NEED  (WD_BYTES + XP_BYTES)
// LDS: A0 [0,32K) A1 [32K,64K) B0 [64K,92K) B1 [92K,120K)
#define ABUF 32768
#define BBUF 28672
#define BOFF 65536
#define LDS_TOT 122880

// ---------------- fused preprocessing ----------------
__global__ __launch_bounds__(256) void preproc(
    const float* __restrict__ x, const float* __restrict__ wv,
    const int* __restrict__ widx, __hip_bfloat16* __restrict__ wd,
    __hip_bfloat16* __restrict__ xp)
{
    int bid = blockIdx.x;
    int tid = threadIdx.x;
    if (bid >= 1792) {              // ---- scatter_w ----
        int o = bid - 1792;
        int j = tid & 63;
        if (tid < 64) {
#pragma unroll
            for (int k = 0; k < 9; ++k)
                reinterpret_cast<float2*>(wd + (size_t)k * 65536 + o * 256)[j] =
                    float2{0.f, 0.f};
        }
        __syncthreads();
        if (tid < 64) {
            int cin = widx[o * 64 + j];
            const float* src = wv + (size_t)(o * 64 + j) * 9;
#pragma unroll
            for (int k = 0; k < 9; ++k)
                wd[(size_t)k * 65536 + o * 256 + cin] = __float2bfloat16(src[k]);
        }
        return;
    }
    // ---- x_to_nhwc ----
    int b = bid / 56, h = bid - (bid / 56) * 56;
    __shared__ __hip_bfloat16 tile[56][264];
    int c = tid;
    const float* src = x + ((size_t)(b * 256 + c)) * 3136 + h * 56;
    float vals[56];
#pragma unroll
    for (int i = 0; i < 14; ++i) {
        float4 v = *reinterpret_cast<const float4*>(src + i * 4);
        vals[i*4+0] = v.x; vals[i*4+1] = v.y; vals[i*4+2] = v.z; vals[i*4+3] = v.w;
    }
#pragma unroll
    for (int w = 0; w < 56; ++w) tile[w][c] = __float2bfloat16(vals[w]);

    char* rowb = (char*)xp + (((size_t)b * 58 + (h + 1)) * 58) * 512;
    if (tid < 64)        reinterpret_cast<double*>(rowb)[tid] = 0.0;
    else if (tid < 128)  *reinterpret_cast<double*>(rowb + 57 * 512 + (tid - 64) * 8) = 0.0;
    if (h == 0) {
        char* r0 = (char*)xp + (((size_t)b * 58 + 0) * 58) * 512;
        for (int i = tid; i < 58 * 64; i += 256) reinterpret_cast<double*>(r0)[i] = 0.0;
    }
    if (h == 55) {
        char* r57 = (char*)xp + (((size_t)b * 58 + 57) * 58) * 512;
        for (int i = tid; i < 58 * 64; i += 256) reinterpret_cast<double*>(r57)[i] = 0.0;
    }

    __syncthreads();
    char* obase = (char*)xp + (((size_t)b * 58 + (h + 1)) * 58) * 512;
#pragma unroll
    for (int k = 0; k < 7; ++k) {
        int i = tid + k * 256;
        int w = i >> 5, cc = i & 31;
        bf16x8 v = *reinterpret_cast<const bf16x8*>(&tile[w][cc * 8]);
        *reinterpret_cast<bf16x8*>(obase + (size_t)(w + 1) * 512 + cc * 16) = v;
    }
}

// ---------------- GEMM ----------------

__device__ __forceinline__ void gload_lds16(const void* g, void* l) {
    __builtin_amdgcn_global_load_lds(
        (const __attribute__((address_space(1))) void*)g,
        (__attribute__((address_space(3))) void*)l, 16, 0, 0);
}

template<int BB, int J>
__device__ __forceinline__ void stage_a(const char* wdB, char* smem, int wid,
                                        int sa_off, int aoff) {
    gload_lds16(wdB + aoff + J * 64 * 512 + sa_off,
                smem + BB * ABUF + (J * 64 + wid * 8) * 128);
}

template<int BB, int J>
__device__ __forceinline__ void stage_b(const char* xpB, char* smem, int wid,
                                        int pbJ, int boff) {
    gload_lds16(xpB + pbJ + boff,
                smem + BOFF + BB * BBUF + (J * 64 + wid * 8) * 128);
}

__device__ __forceinline__ int pixoff(int p) {
    int b = p / 3136; int r = p - b * 3136;
    int h = r / 56;   int w = r - h * 56;
    return ((b * 58 + h + 1) * 58 + (w + 1)) * 512;
}

__device__ __forceinline__ int aoff_t(int t) {
    return (t >> 2) * 131072 + (t & 3) * 128;
}
__device__ __forceinline__ int boff_t(int t) {
    int k9 = t >> 2; int kh = k9 / 3; int kw = k9 - 3 * kh;
    return ((kh - 1) * 58 + (kw - 1)) * 512 + (t & 3) * 128;
}

#define BAR() __builtin_amdgcn_s_barrier()
#define VMCNT0() asm volatile("s_waitcnt vmcnt(0)" ::: "memory")

// One K-tile on buf U; stages tile tn into buf 1-U. Reads in consumption
// order: {af0[0], bf0[0..6], af0[1..3]} -> stages -> {s1 set} -> 28 MFMA(s0)
// -> 28 MFMA(s1). First MFMA gated on 2 reads; s1 reads fly under s0 MFMAs.
template<int U>
__device__ __forceinline__ void ktile(
    const char* wdB, const char* xpB, char* smem,
    int wid, int wr, int wc, int a_rb, int xq0, int xq1, int sa_off,
    int pb0, int pb1, int pb2, int pb3,
    int tn, f32x4 (&acc)[4][7])
{
    const int aBase = U * ABUF + wr * 64 * 128 + a_rb;
    const int bBase = BOFF + U * BBUF + wc * 112 * 128 + a_rb;

    bf16x8 af0[4], bf0[7], af1[4], bf1[7];
    // ---- k-slice 0 reads, unlock order ----
    af0[0] = *(const bf16x8*)(smem + aBase + xq0);
#pragma unroll
    for (int ni = 0; ni < 7; ++ni)
        bf0[ni] = *(const bf16x8*)(smem + bBase + ni * 16 * 128 + xq0);
#pragma unroll
    for (int mi = 1; mi < 4; ++mi)
        af0[mi] = *(const bf16x8*)(smem + aBase + mi * 16 * 128 + xq0);

    // ---- stage tile tn -> buf 1-U (VMEM issue; lands under this K-tile) ----
    const int an = aoff_t(tn), bn = boff_t(tn);
    stage_a<1-U,0>(wdB, smem, wid, sa_off, an);
    stage_a<1-U,1>(wdB, smem, wid, sa_off, an);
    stage_a<1-U,2>(wdB, smem, wid, sa_off, an);
    stage_a<1-U,3>(wdB, smem, wid, sa_off, an);
    stage_b<1-U,0>(xpB, smem, wid, pb0, bn);
    stage_b<1-U,1>(xpB, smem, wid, pb1, bn);
    stage_b<1-U,2>(xpB, smem, wid, pb2, bn);
    if (wid < 4) stage_b<1-U,3>(xpB, smem, wid, pb3, bn);

    // ---- k-slice 1 reads (in flight under s0 MFMAs) ----
    af1[0] = *(const bf16x8*)(smem + aBase + xq1);
#pragma unroll
    for (int ni = 0; ni < 7; ++ni)
        bf1[ni] = *(const bf16x8*)(smem + bBase + ni * 16 * 128 + xq1);
#pragma unroll
    for (int mi = 1; mi < 4; ++mi)
        af1[mi] = *(const bf16x8*)(smem + aBase + mi * 16 * 128 + xq1);

    __builtin_amdgcn_s_setprio(1);
#pragma unroll
    for (int mi = 0; mi < 4; ++mi)
#pragma unroll
        for (int ni = 0; ni < 7; ++ni)
            acc[mi][ni] = __builtin_amdgcn_mfma_f32_16x16x32_bf16(
                af0[mi], bf0[ni], acc[mi][ni], 0, 0, 0);
#pragma unroll
    for (int mi = 0; mi < 4; ++mi)
#pragma unroll
        for (int ni = 0; ni < 7; ++ni)
            acc[mi][ni] = __builtin_amdgcn_mfma_f32_16x16x32_bf16(
                af1[mi], bf1[ni], acc[mi][ni], 0, 0, 0);
    __builtin_amdgcn_s_setprio(0);

    VMCNT0();   // stage(tn) drained; issued ~4000 wall-cyc ago -> cheap
    BAR();      // buf 1-U ready; all waves done reading buf U
}

__global__ __launch_bounds__(512, 2) void sparse_conv_mfma224(
    const __hip_bfloat16* __restrict__ wd, const __hip_bfloat16* __restrict__ xp,
    float* __restrict__ out)
{
    extern __shared__ char smem[];
    const char* wdB = (const char*)wd;
    const char* xpB = (const char*)xp;

    // bijective XCD swizzle: 448 = 8 * 56; consecutive nt on one XCD's L2
    const int bid = blockIdx.x;
    const int nt = (bid & 7) * 56 + (bid >> 3);

    const int t = threadIdx.x;
    const int lane = t & 63, wid = t >> 6;   // 8 waves
    const int wr = wid >> 1, wc = wid & 1;   // 4M x 2N wave grid

    const int axor = (((lane & 7) ^ (lane >> 3)) * 16);
    const int sa_off = (wid * 8 + (lane >> 3)) * 512 + axor;
    const int prow = wid * 8 + (lane >> 3);
    const int pb0 = pixoff(nt * 224 +   0 + prow) + axor;
    const int pb1 = pixoff(nt * 224 +  64 + prow) + axor;
    const int pb2 = pixoff(nt * 224 + 128 + prow) + axor;
    const int pb3 = (wid < 4) ? (pixoff(nt * 224 + 192 + prow) + axor) : 0;

    const int a_rb = (lane & 15) * 128;
    const int xq0 = (((lane >> 4)) ^ (lane & 7)) * 16;
    const int xq1 = ((4 + (lane >> 4)) ^ (lane & 7)) * 16;

    f32x4 acc[4][7] = {};

    // ---- prologue: stage tile 0 -> buf0 ----
    {
        const int a0 = aoff_t(0), b0 = boff_t(0);
        stage_a<0,0>(wdB, smem, wid, sa_off, a0);
        stage_a<0,1>(wdB, smem, wid, sa_off, a0);
        stage_a<0,2>(wdB, smem, wid, sa_off, a0);
        stage_a<0,3>(wdB, smem, wid, sa_off, a0);
        stage_b<0,0>(xpB, smem, wid, pb0, b0);
        stage_b<0,1>(xpB, smem, wid, pb1, b0);
        stage_b<0,2>(xpB, smem, wid, pb2, b0);
        if (wid < 4) stage_b<0,3>(xpB, smem, wid, pb3, b0);
        VMCNT0();
        BAR();
    }

    // ---- main loop: 18 iterations x 2 K-tiles (36 total) ----
    for (int it = 0; it < 18; ++it) {
        const int t1 = 2 * it + 1;
        int t2 = t1 + 1; if (t2 == 36) t2 = 0;   // wrapped dead staging
        ktile<0>(wdB, xpB, smem, wid, wr, wc, a_rb, xq0, xq1, sa_off,
                 pb0, pb1, pb2, pb3, t1, acc);
        ktile<1>(wdB, xpB, smem, wid, wr, wc, a_rb, xq0, xq1, sa_off,
                 pb0, pb1, pb2, pb3, t2, acc);
    }

    // ---- epilogue: out[b][o][px] ----
#pragma unroll
    for (int n = 0; n < 7; ++n) {
        int p0 = nt * 224 + wc * 112 + n * 16;   // wave-uniform; 16 | 3136
        int pb = p0 / 3136;
        int rem0 = p0 - pb * 3136;
#pragma unroll
        for (int m = 0; m < 4; ++m) {
            int o = wr * 64 + m * 16 + (lane >> 4) * 4;
            float* dst = out + ((size_t)(pb * 256 + o)) * 3136 + rem0 + (lane & 15);
#pragma unroll
            for (int r = 0; r < 4; ++r) dst[(size_t)r * 3136] = acc[m][n][r];
        }
    }
}

// ---------------- fallback (ws too small) ----------------

__global__ __launch_bounds__(256) void sparse_conv_direct(
    const float* __restrict__ x, const float* __restrict__ wv,
    const int* __restrict__ widx, float* __restrict__ out)
{
    const int bid = blockIdx.x;
    const int b = bid >> 8, o = bid & 255;
    const int tid = threadIdx.x;
    __shared__ float plane[58 * 60];
    const int rt = tid >> 3, ct = tid & 7;
    const int r0 = rt * 2, c0 = ct * 7;
    const bool active = (rt < 28);
    float acc[2][7];
#pragma unroll
    for (int i = 0; i < 2; ++i)
#pragma unroll
        for (int c = 0; c < 7; ++c) acc[i][c] = 0.f;
    const float* xb = x + (size_t)b * 256 * 3136;
    const int* idxp = widx + o * 64;
    const float* wp0 = wv + (size_t)o * 64 * 9;
    for (int j = 0; j < 64; ++j) {
        const int cin = idxp[j];
        const float* src = xb + cin * 3136;
        __syncthreads();
        for (int i = tid; i < 58 * 58; i += 256) {
            const int r = i / 58, c = i - r * 58;
            const int h = r - 1, w = c - 1;
            float v = 0.f;
            if ((unsigned)h < 56u && (unsigned)w < 56u) v = src[h * 56 + w];
            plane[r * 60 + c] = v;
        }
        float wreg[9];
#pragma unroll
        for (int k = 0; k < 9; ++k) wreg[k] = wp0[j * 9 + k];
        __syncthreads();
        if (active) {
            float rows[4][9];
#pragma unroll
            for (int dr = 0; dr < 4; ++dr)
#pragma unroll
                for (int cc = 0; cc < 9; ++cc)
                    rows[dr][cc] = plane[(r0 + dr) * 60 + (c0 + cc)];
#pragma unroll
            for (int i = 0; i < 2; ++i)
#pragma unroll
                for (int cc = 0; cc < 7; ++cc) {
                    float s = acc[i][cc];
#pragma unroll
                    for (int kh = 0; kh < 3; ++kh)
#pragma unroll
                        for (int kw = 0; kw < 3; ++kw)
                            s += rows[i + kh][cc + kw] * wreg[kh * 3 + kw];
                    acc[i][cc] = s;
                }
        }
    }
    if (active) {
        float* op = out + (size_t)bid * 3136;
#pragma unroll
        for (int i = 0; i < 2; ++i)
#pragma unroll
            for (int cc = 0; cc < 7; ++cc)
                op[(r0 + i) * 56 + (c0 + cc)] = acc[i][cc];
    }
}

extern "C" void kernel_launch(void* const* d_in, const int* in_sizes, int n_in,
                              void* d_out, int out_size, void* d_ws, size_t ws_size,
                              hipStream_t stream) {
    const float* x    = (const float*)d_in[0];
    const float* wv   = (const float*)d_in[1];
    const int*   widx = (const int*)d_in[2];
    float* out = (float*)d_out;
    (void)in_sizes; (void)n_in; (void)out_size;

    if (ws_size < (size_t)WS_NEED) {
        sparse_conv_direct<<<dim3(32 * 256), dim3(256), 0, stream>>>(x, wv, widx, out);
        return;
    }

    __hip_bfloat16* wd = (__hip_bfloat16*)d_ws;
    __hip_bfloat16* xp = (__hip_bfloat16*)((char*)d_ws + WD_BYTES);

    preproc<<<dim3(32 * 56 + 256), dim3(256), 0, stream>>>(x, wv, widx, wd, xp);

    (void)hipFuncSetAttribute((const void*)sparse_conv_mfma224,
                              hipFuncAttributeMaxDynamicSharedMemorySize, LDS_TOT);
    sparse_conv_mfma224<<<dim3(448), dim3(512), LDS_TOT, stream>>>(wd, xp, out);
}